// Round 2
// baseline (1880.956 us; speedup 1.0000x reference)
//
#include <hip/hip_runtime.h>
#include <hip/hip_bf16.h>
#include <math.h>

// Problem dims (fixed by setup_inputs)
#define MTOK 4096
#define DDIM 1024
#define NEXP 16
#define PSLOT 1024
#define NPDIM 16384   // NEXP*PSLOT
#define HDIM 1365
#define HPAD 1376     // HDIM rounded to multiple of 32 (K-tile), 16B-aligned rows
#define KSPL 4        // split-K factor for the final combine GEMM

typedef unsigned short u16;  // raw bf16
typedef __attribute__((ext_vector_type(8))) short short8;     // MFMA A/B frag (8 bf16)
typedef __attribute__((ext_vector_type(8))) unsigned short ushort8;
typedef __attribute__((ext_vector_type(4))) float f32x4;      // MFMA C/D frag

__device__ __forceinline__ float b2f(u16 v) {
    union { unsigned int u; float f; } x;
    x.u = ((unsigned int)v) << 16;
    return x.f;
}
// HW RTNE convert: compiler fuses adjacent pairs into v_cvt_pk_bf16_f32.
__device__ __forceinline__ u16 f2b(float f) {
    __hip_bfloat16 h = __float2bfloat16(f);
    u16 r;
    __builtin_memcpy(&r, &h, 2);
    return r;
}
__device__ __forceinline__ float ldv(const float* p, long long i) { return p[i]; }
__device__ __forceinline__ float ldv(const u16*  p, long long i) { return b2f(p[i]); }
__device__ __forceinline__ void stv(float* p, long long i, float v) { p[i] = v; }
__device__ __forceinline__ void stv(u16*  p, long long i, float v) { p[i] = f2b(v); }

// ---------------------------------------------------------------------------
// MFMA GEMM: C[M,N] = A' * B (+bias)(relu)(*rowsc), fp32 accumulate.
//   AMODE 0: A is bf16 [M,K] row-major -> global_load_lds (dims must be exact)
//   AMODE 2: A is bf16 [K,M] row-major (logical A^T), scaled by S[k][col&1023]
//            (u32 raw loads of bf16 pairs + float2 scale loads)
//   B is [K,N] row-major (fp32 or bf16), transpose-staged to Bs[n][k].
//   BCHK=true: per-tile wave-uniform bounds test vs (Kb, Nb); full tiles take
//              the unchecked vector path, edge tiles the scalar checked path.
//   BCHK=false: statically in-bounds; bf16 B raw-copied (u32), fp32 scalar.
//   Epilogue: col<N -> value; N<=col<NZ -> 0 (pad-zeroing); col>=NZ skip.
// 256 threads, 128x128 tile, BK=32, 4 waves (2x2), 4x4 16x16x32 frags/wave.
// Split-K: launch with blockIdx.z indexing K-chunks via (sA, sB, sC) strides.
// ---------------------------------------------------------------------------
template<int AMODE, typename TA, typename TB, typename TC,
         bool BIASF, bool RELUF, bool ROWSC, bool BCHK>
__global__ __launch_bounds__(256) void mgemm(
    const TA* __restrict__ A, long long sA, int lda,
    const TB* __restrict__ B, long long sB, int ldb,
    TC* __restrict__ C, long long sC, int ldc,
    const float* __restrict__ S,
    const float* __restrict__ bias, long long sBias,
    const float* __restrict__ rowsc,
    int M, int N, int NZ, int K, int Kb, int Nb)
{
    constexpr int AS = (AMODE == 0) ? 32 : 40;  // As row stride (elements)
    constexpr int BS = 40;                      // Bs row stride (elements)
    __shared__ u16 As[128 * AS];
    __shared__ u16 Bs[128 * BS];

    const int bz = blockIdx.z;
    A += (long long)bz * sA;
    B += (long long)bz * sB;
    C += (long long)bz * sC;
    const float* biasp = BIASF ? (bias + (long long)bz * sBias) : nullptr;

    const int m0 = blockIdx.y * 128;
    const int n0 = blockIdx.x * 128;
    const int tid  = threadIdx.x;
    const int lane = tid & 63;
    const int wv   = tid >> 6;       // wave 0..3
    const int wm   = wv & 1;         // wave row (2x2)
    const int wn   = wv >> 1;        // wave col
    const int quad = lane >> 4;
    const int l16  = lane & 15;

    f32x4 acc[4][4];
#pragma unroll
    for (int i = 0; i < 4; ++i)
#pragma unroll
        for (int j = 0; j < 4; ++j) acc[i][j] = (f32x4){0.f, 0.f, 0.f, 0.f};

    for (int k0 = 0; k0 < K; k0 += 32) {
        // ---------------- stage A -> As[m][k] ----------------
        if constexpr (AMODE == 0) {
            // direct-to-LDS DMA: rows 64B, dest = wave-uniform base + lane*16
#pragma unroll
            for (int q = 0; q < 2; ++q) {
                const u16* gp = A + (long long)(m0 + wv * 32 + q * 16 + (lane >> 2)) * lda
                                  + k0 + (lane & 3) * 8;
                u16* lp = &As[(wv * 32 + q * 16) * 32];  // wave-uniform
                __builtin_amdgcn_global_load_lds(
                    (const __attribute__((address_space(1))) unsigned int*)gp,
                    (__attribute__((address_space(3))) unsigned int*)lp, 16, 0, 0);
            }
        } else {
            // bf16 [K,M] + scale: thread patch = 8(k) x 2(m); u32 + float2 loads
            const int o = tid >> 6, p = tid & 63;
            const int mloc = 2 * p;
            ushort8 va, vb;
#pragma unroll
            for (int i = 0; i < 8; ++i) {
                const long long kg = k0 + o * 8 + i;
                const unsigned int raw =
                    *(const unsigned int*)((const u16*)A + kg * lda + (m0 + mloc));
                const float2 s = *(const float2*)&S[kg * 1024 + ((m0 + mloc) & 1023)];
                va[i] = f2b(b2f((u16)(raw & 0xFFFFu)) * s.x);
                vb[i] = f2b(b2f((u16)(raw >> 16)) * s.y);
            }
            *(ushort8*)&As[mloc * AS + o * 8]       = va;
            *(ushort8*)&As[(mloc + 1) * AS + o * 8] = vb;
        }

        // ---------------- stage B [K,N] -> Bs[n][k] ----------------
        {
            const int o = tid >> 6, p = tid & 63;
            const int nloc = 2 * p;
            const int ng0 = n0 + nloc, ng1 = ng0 + 1;
            ushort8 va, vb;
            bool full = true;
            if constexpr (BCHK) full = (k0 + 32 <= Kb) && (n0 + 128 <= Nb);
            if (full) {
                // whole tile statically/dynamically in-bounds: no checks
#pragma unroll
                for (int i = 0; i < 8; ++i) {
                    const int kg = k0 + o * 8 + i;
                    if constexpr (sizeof(TB) == 2) {
                        // bf16: raw copy (u32 = 2 adjacent cols)
                        const unsigned int raw =
                            *(const unsigned int*)((const u16*)B + (long long)kg * ldb + ng0);
                        va[i] = (u16)(raw & 0xFFFFu);
                        vb[i] = (u16)(raw >> 16);
                    } else {
                        // fp32: 2 scalar loads (ldb may be odd -> no float2)
                        const float* bp = (const float*)B + (long long)kg * ldb + ng0;
                        va[i] = f2b(bp[0]);
                        vb[i] = f2b(bp[1]);
                    }
                }
            } else {
#pragma unroll
                for (int i = 0; i < 8; ++i) {
                    const int kg = k0 + o * 8 + i;
                    float v0 = 0.f, v1 = 0.f;
                    if (kg < Kb) {
                        if (ng0 < Nb) v0 = ldv(B, (long long)kg * ldb + ng0);
                        if (ng1 < Nb) v1 = ldv(B, (long long)kg * ldb + ng1);
                    }
                    va[i] = f2b(v0);
                    vb[i] = f2b(v1);
                }
            }
            *(ushort8*)&Bs[nloc * BS + o * 8]       = va;
            *(ushort8*)&Bs[(nloc + 1) * BS + o * 8] = vb;
        }
        __syncthreads();

        // ---------------- MFMA ----------------
        short8 bfr[4];
#pragma unroll
        for (int ni = 0; ni < 4; ++ni)
            bfr[ni] = *(const short8*)&Bs[(wn * 64 + ni * 16 + l16) * BS + quad * 8];
#pragma unroll
        for (int mi = 0; mi < 4; ++mi) {
            short8 a = *(const short8*)&As[(wm * 64 + mi * 16 + l16) * AS + quad * 8];
#pragma unroll
            for (int ni = 0; ni < 4; ++ni)
                acc[mi][ni] = __builtin_amdgcn_mfma_f32_16x16x32_bf16(a, bfr[ni], acc[mi][ni], 0, 0, 0);
        }
        __syncthreads();
    }

    // ---------------- epilogue ----------------
#pragma unroll
    for (int mi = 0; mi < 4; ++mi) {
#pragma unroll
        for (int r = 0; r < 4; ++r) {
            const int rg = m0 + wm * 64 + mi * 16 + quad * 4 + r;
            if (rg >= M) continue;
            const float rs = ROWSC ? rowsc[rg] : 1.f;
#pragma unroll
            for (int ni = 0; ni < 4; ++ni) {
                const int cg = n0 + wn * 64 + ni * 16 + l16;
                if (cg < N) {
                    float v = acc[mi][ni][r];
                    if (BIASF) v += biasp[cg];
                    if (RELUF) v = fmaxf(v, 0.f);
                    if (ROWSC) v *= rs;
                    stv(C, (long long)rg * ldc + cg, v);
                } else if (cg < NZ) {
                    stv(C, (long long)rg * ldc + cg, 0.f);  // zero K-pad cols
                }
            }
        }
    }
}

// ---------------------------------------------------------------------------
// fp32 -> bf16 bulk convert (8 elems/thread, exact grids)
// ---------------------------------------------------------------------------
__global__ __launch_bounds__(256) void cvt_k(
    const float* __restrict__ src, u16* __restrict__ dst, long long n)
{
    const long long i = ((long long)blockIdx.x * 256 + threadIdx.x) * 8;
    if (i >= n) return;
    const float4 a = *(const float4*)&src[i];
    const float4 b = *(const float4*)&src[i + 4];
    ushort8 v;
    v[0] = f2b(a.x); v[1] = f2b(a.y); v[2] = f2b(a.z); v[3] = f2b(a.w);
    v[4] = f2b(b.x); v[5] = f2b(b.y); v[6] = f2b(b.z); v[7] = f2b(b.w);
    *(ushort8*)&dst[i] = v;
}

// ---------------------------------------------------------------------------
// Softmax pass over bf16 logits: L[m,:] -> E = exp(L - rowmax) in place (bf16);
//   rsc[m] = 1/sum(E);  rsd[m,p] = 1/sum_n E[m, n*P + p]   (fp32 outputs)
// Vectorized ushort8 loads/stores; exact coverage (2048 lanes*8 = 16384).
// ---------------------------------------------------------------------------
__global__ __launch_bounds__(256) void softmax_k(
    u16* __restrict__ L, float* __restrict__ rsd, float* __restrict__ rsc)
{
    const int m = blockIdx.x;
    u16* row = L + (long long)m * NPDIM;
    const int tid = threadIdx.x;
    __shared__ float red[256];

    float mx = -1e30f;
    for (int i = tid * 8; i < NPDIM; i += 2048) {
        const ushort8 v = *(const ushort8*)&row[i];
#pragma unroll
        for (int j = 0; j < 8; ++j) mx = fmaxf(mx, b2f(v[j]));
    }
    red[tid] = mx;
    __syncthreads();
    for (int s = 128; s > 0; s >>= 1) {
        if (tid < s) red[tid] = fmaxf(red[tid], red[tid + s]);
        __syncthreads();
    }
    const float mxAll = red[0];
    __syncthreads();

    float sum = 0.f;
    for (int i = tid * 8; i < NPDIM; i += 2048) {
        const ushort8 v = *(const ushort8*)&row[i];
        ushort8 e;
#pragma unroll
        for (int j = 0; j < 8; ++j) {
            const float ef = __expf(b2f(v[j]) - mxAll);
            const u16 eb = f2b(ef);
            e[j] = eb;
            sum += b2f(eb);
        }
        *(ushort8*)&row[i] = e;
    }
    red[tid] = sum;
    __syncthreads();
    for (int s = 128; s > 0; s >>= 1) {
        if (tid < s) red[tid] += red[tid + s];
        __syncthreads();
    }
    if (tid == 0) rsc[m] = 1.f / red[0];
    __syncthreads();

    {   // rsd: 4 consecutive p per thread (256*4 = 1024)
        const int p0 = tid * 4;
        float s0 = 0.f, s1 = 0.f, s2 = 0.f, s3 = 0.f;
#pragma unroll
        for (int n = 0; n < NEXP; ++n) {
            const ushort4 v = *(const ushort4*)&row[n * PSLOT + p0];
            s0 += b2f(v.x); s1 += b2f(v.y); s2 += b2f(v.z); s3 += b2f(v.w);
        }
        const float4 r = {1.f / s0, 1.f / s1, 1.f / s2, 1.f / s3};
        *(float4*)&rsd[(long long)m * PSLOT + p0] = r;
    }
}

// ---------------------------------------------------------------------------
// Sum the KSPL split-K partials -> Y.  Grid sized exactly: MTOK*PSLOT/(4*256).
// ---------------------------------------------------------------------------
__global__ __launch_bounds__(256) void reduce_k(
    const float* __restrict__ Yp, float* __restrict__ Y)
{
    const long long S = (long long)MTOK * PSLOT;
    const long long i = ((long long)blockIdx.x * 256 + threadIdx.x) * 4;
    f32x4 r = *(const f32x4*)&Yp[i];
#pragma unroll
    for (int z = 1; z < KSPL; ++z) r += *(const f32x4*)&Yp[(long long)z * S + i];
    *(f32x4*)&Y[i] = r;
}

extern "C" void kernel_launch(void* const* d_in, const int* in_sizes, int n_in,
                              void* d_out, int out_size, void* d_ws, size_t ws_size,
                              hipStream_t stream)
{
    const float* x   = (const float*)d_in[0];  // [4096,1024]
    const float* phi = (const float*)d_in[1];  // [1024,16,1024]
    const float* W1  = (const float*)d_in[2];  // [16,1024,1365]
    const float* b1  = (const float*)d_in[3];  // [16,1365]
    const float* W2  = (const float*)d_in[4];  // [16,1365,1024]
    const float* b2  = (const float*)d_in[5];  // [16,1024]
    float* Y = (float*)d_out;                  // [4096,1024] fp32

    // Workspace (~253 MB, same budget as the passing layout).
    // Aliases (lifetime-disjoint):
    //   phib (32 MB) overlays Ys   [phib: pre -> step1; Ys: step5 -> step6]
    //   xb   ( 8 MB) overlays Hb   [xb:   pre -> step3; Hb: step4 -> step5]
    //   Yp   (64 MB) overlays rsd+Xs+Hb [all dead by step 6]
    char* w = (char*)d_ws;
    u16*   L    = (u16*)w;   w += (size_t)MTOK * NPDIM * 2;          // 128 MB (logits -> E)
    u16*   Ys   = (u16*)w;   w += (size_t)NEXP * PSLOT * PSLOT * 2;  // 32 MB
    float* rsc  = (float*)w; w += (size_t)MTOK * 4;                  // 16 KB
    float* Yp   = (float*)w;                                         // 64 MB alias
    float* rsd  = (float*)w; w += (size_t)MTOK * PSLOT * 4;          // 16 MB
    u16*   Xs   = (u16*)w;   w += (size_t)NEXP * PSLOT * DDIM * 2;   // 32 MB
    u16*   Hb   = (u16*)w;   w += (size_t)NEXP * PSLOT * HPAD * 2;   // 45.1 MB
    u16*   phib = Ys;                                                // bf16 phi
    u16*   xb   = Hb;                                                // bf16 x

    // 0) one-shot bf16 conversions of x and phi
    cvt_k<<<dim3((MTOK * DDIM) / (8 * 256)), 256, 0, stream>>>(x, xb, (long long)MTOK * DDIM);
    cvt_k<<<dim3((DDIM * NPDIM) / (8 * 256)), 256, 0, stream>>>(phi, phib, (long long)DDIM * NPDIM);

    // 1) L = xb @ phib   [4096,16384], K=1024  (AMODE 0 DMA + raw-u32 B)
    mgemm<0, u16, u16, u16, false, false, false, false>
        <<<dim3(NPDIM / 128, MTOK / 128, 1), 256, 0, stream>>>(
        xb, 0, DDIM,  phib, 0, NPDIM,  L, 0, NPDIM,
        nullptr, nullptr, 0, nullptr,
        MTOK, NPDIM, NPDIM, DDIM, DDIM, NPDIM);

    // 2) E = exp(L - max) in place; rsd, rsc
    softmax_k<<<dim3(MTOK), 256, 0, stream>>>(L, rsd, rsc);

    // 3) Xs[np,d] = sum_m (E*rsd)[m,np] * x[m,d]   (A^T staging + scale, K=4096)
    mgemm<2, u16, u16, u16, false, false, false, false>
        <<<dim3(DDIM / 128, NPDIM / 128, 1), 256, 0, stream>>>(
        L, 0, NPDIM,  xb, 0, DDIM,  Xs, 0, DDIM,
        rsd, nullptr, 0, nullptr,
        NPDIM, DDIM, DDIM, MTOK, MTOK, DDIM);

    // 4) H = relu(Xs @ W1 + b1) per expert  [1024,1365]->[1024,1376], K=1024
    mgemm<0, u16, float, u16, true, true, false, true>
        <<<dim3((HPAD + 127) / 128, PSLOT / 128, NEXP), 256, 0, stream>>>(
        Xs, (long long)PSLOT * DDIM, DDIM,
        W1, (long long)DDIM * HDIM, HDIM,
        Hb, (long long)PSLOT * HPAD, HPAD,
        nullptr, b1, HDIM, nullptr,
        PSLOT, HDIM, HPAD, DDIM, DDIM, HDIM);

    // 5) Ys = H @ W2 + b2 per expert  [1024,1024], K=1376 (pad zeros both sides)
    mgemm<0, u16, float, u16, true, false, false, true>
        <<<dim3(PSLOT / 128, PSLOT / 128, NEXP), 256, 0, stream>>>(
        Hb, (long long)PSLOT * HPAD, HPAD,
        W2, (long long)HDIM * PSLOT, PSLOT,
        Ys, (long long)PSLOT * PSLOT, PSLOT,
        nullptr, b2, PSLOT, nullptr,
        PSLOT, PSLOT, PSLOT, HPAD, HDIM, PSLOT);

    // 6) Y[m,o] = rsc[m] * sum_np E[m,np] * Ys[np,o]   [4096,1024], K=16384
    //    Split-K x4: 1024 blocks (4/CU) so TLP hides staging latency.
    mgemm<0, u16, u16, float, false, false, true, false>
        <<<dim3(PSLOT / 128, MTOK / 128, KSPL), 256, 0, stream>>>(
        L, (long long)(NPDIM / KSPL), NPDIM,
        Ys, (long long)(NPDIM / KSPL) * PSLOT, PSLOT,
        Yp, (long long)MTOK * PSLOT, PSLOT,
        nullptr, nullptr, 0, rsc,
        MTOK, PSLOT, PSLOT, NPDIM / KSPL, NPDIM / KSPL, PSLOT);

    // 7) Y = sum_z Yp[z]
    reduce_k<<<dim3((MTOK * PSLOT) / (4 * 256)), 256, 0, stream>>>(Yp, Y);
}

// Round 3
// 1373.513 us; speedup vs baseline: 1.3694x; 1.3694x over previous
//
#include <hip/hip_runtime.h>
#include <math.h>

// Problem dims (fixed by setup_inputs)
#define MTOK 4096
#define DDIM 1024
#define NEXP 16
#define PSLOT 1024
#define NPDIM 16384   // NEXP*PSLOT
#define HDIM 1365
#define HPAD 1376     // HDIM rounded to multiple of 32 (K-tile), 16B-aligned rows
#define KSPL 4        // split-K factor for the final combine GEMM

typedef unsigned short u16;  // raw bf16
typedef __attribute__((ext_vector_type(8))) short short8;     // MFMA A/B frag (8 bf16)
typedef __attribute__((ext_vector_type(8))) unsigned short ushort8;
typedef __attribute__((ext_vector_type(4))) float f32x4;      // MFMA C/D frag

template<bool Bc, typename T, typename F> struct cond_t { using type = T; };
template<typename T, typename F> struct cond_t<false, T, F> { using type = F; };

__device__ __forceinline__ float b2f(u16 v) {
    union { unsigned int u; float f; } x;
    x.u = ((unsigned int)v) << 16;
    return x.f;
}
// integer RTNE (R1-measured faster than __float2bfloat16 across all kernels)
__device__ __forceinline__ u16 f2b(float f) {
    union { float f; unsigned int u; } x;
    x.f = f;
    unsigned int r = x.u + 0x7FFFu + ((x.u >> 16) & 1u);
    return (u16)(r >> 16);
}
__device__ __forceinline__ void stv(float* p, long long i, float v) { p[i] = v; }
__device__ __forceinline__ void stv(u16*  p, long long i, float v) { p[i] = f2b(v); }

// ---------------------------------------------------------------------------
// MFMA GEMM: C[M,N] = A' * B (+bias)(relu)(*rowsc), fp32 accumulate.
//   AMODE 0: A is bf16 [M,K] row-major -> global_load_lds (dims must be exact)
//   AMODE 2: A is bf16 [K,M] row-major (logical A^T), scaled by S[k][col&1023]
//   B is [K,N] row-major (fp32 or bf16), transpose-staged to Bs[n][k].
//   BCHK: per-tile wave-uniform bounds test vs (Kb, Nb); edge tiles scalar.
// 256 threads, 128x128 tile, BK=32, 4 waves (2x2), 4x4 16x16x32 frags/wave.
// 2-phase pipeline: dbuf LDS; issue tile t+1 loads (DMA / raw->regs) BEFORE
// the MFMA on tile t; convert+ds_write after; ONE __syncthreads per K-step
// (its vmcnt(0)+lgkmcnt(0) drain is exactly the wait needed; load latency
// hides under 64 MFMAs). Writes hit buf nxt whose readers finished before
// the previous barrier -> race-free with a single barrier.
// XCD-chunked swizzle: blocks sharing an operand panel land on one XCD.
// ---------------------------------------------------------------------------
template<int AMODE, typename TA, typename TB, typename TC,
         bool BIASF, bool RELUF, bool ROWSC, bool BCHK>
__global__ __launch_bounds__(256) void mgemm(
    const TA* __restrict__ A, long long sA, int lda,
    const TB* __restrict__ B, long long sB, int ldb,
    TC* __restrict__ C, long long sC, int ldc,
    const float* __restrict__ S,
    const float* __restrict__ bias, long long sBias,
    const float* __restrict__ rowsc,
    int M, int N, int NZ, int K, int Kb, int Nb)
{
    constexpr int AS = (AMODE == 0) ? 32 : 40;  // As row stride (elements)
    constexpr int BS = 40;                      // Bs row stride (elements)
    __shared__ u16 As[2][128 * AS];
    __shared__ u16 Bs[2][128 * BS];

    const int bz = blockIdx.z;
    A += (long long)bz * sA;
    B += (long long)bz * sB;
    C += (long long)bz * sC;
    const float* biasp = BIASF ? (bias + (long long)bz * sBias) : nullptr;

    // XCD-chunked swizzle (bijective: gx*gy % 8 == 0 for every launch here).
    // Dispatch id b -> xcd ~ b%8; give each xcd a contiguous run of tiles so
    // blocks sharing an A-panel (consecutive x at fixed y) share an L2.
    const int gx = gridDim.x;
    const int nwg = gx * gridDim.y;
    int wg = blockIdx.x + gx * blockIdx.y;
    wg = (wg & 7) * (nwg >> 3) + (wg >> 3);
    const int m0 = (wg / gx) * 128;
    const int n0 = (wg % gx) * 128;

    const int tid  = threadIdx.x;
    const int lane = tid & 63;
    const int wv   = tid >> 6;       // wave 0..3
    const int wm   = wv & 1;         // wave row (2x2)
    const int wn   = wv >> 1;        // wave col
    const int quad = lane >> 4;
    const int l16  = lane & 15;

    // staging coords (one thread covers 2 adjacent cols x 8 k)
    const int pp   = tid & 63;
    const int cl0  = 2 * pp;         // local col pair base (A-col for AMODE2, B-col)
    const int ng0  = n0 + cl0;

    f32x4 acc[4][4];
#pragma unroll
    for (int i = 0; i < 4; ++i)
#pragma unroll
        for (int j = 0; j < 4; ++j) acc[i][j] = (f32x4){0.f, 0.f, 0.f, 0.f};

    using BRAW = typename cond_t<sizeof(TB) == 2, unsigned int[8], float[16]>::type;

    // ---- phase helpers -----------------------------------------------------
    auto LOADA = [&](int k0, int buf, unsigned int (&araw)[8]) {
        if constexpr (AMODE == 0) {
            // direct-to-LDS DMA: rows 64B, dest = wave-uniform base + lane*16
#pragma unroll
            for (int q = 0; q < 2; ++q) {
                const u16* gp = A + (long long)(m0 + wv * 32 + q * 16 + (lane >> 2)) * lda
                                  + k0 + (lane & 3) * 8;
                u16* lp = &As[buf][(wv * 32 + q * 16) * 32];  // wave-uniform
                __builtin_amdgcn_global_load_lds(
                    (const __attribute__((address_space(1))) unsigned int*)gp,
                    (__attribute__((address_space(3))) unsigned int*)lp, 16, 0, 0);
            }
        } else {
            // bf16 [K,M]: raw u32 (2 cols) per k; scale applied at write time
#pragma unroll
            for (int i = 0; i < 8; ++i) {
                const long long kg = k0 + wv * 8 + i;
                araw[i] = *(const unsigned int*)((const u16*)A + kg * lda + (m0 + cl0));
            }
        }
    };
    auto WRITEA = [&](int k0, int buf, unsigned int (&araw)[8]) {
        if constexpr (AMODE != 0) {
            ushort8 va, vb;
#pragma unroll
            for (int i = 0; i < 8; ++i) {
                const long long kg = k0 + wv * 8 + i;
                const float2 s = *(const float2*)&S[kg * 1024 + ((m0 + cl0) & 1023)];
                va[i] = f2b(b2f((u16)(araw[i] & 0xFFFFu)) * s.x);
                vb[i] = f2b(b2f((u16)(araw[i] >> 16)) * s.y);
            }
            *(ushort8*)&As[buf][cl0 * AS + wv * 8]       = va;
            *(ushort8*)&As[buf][(cl0 + 1) * AS + wv * 8] = vb;
        }
    };
    auto LOADB = [&](int k0, BRAW& braw) {
        if constexpr (sizeof(TB) == 2) {
            // bf16 B users are statically in-bounds (BCHK=false): raw u32 copy
#pragma unroll
            for (int i = 0; i < 8; ++i) {
                const int kg = k0 + wv * 8 + i;
                braw[i] = *(const unsigned int*)((const u16*)B + (long long)kg * ldb + ng0);
            }
        } else {
            bool full = true;
            if constexpr (BCHK) full = (k0 + 32 <= Kb) && (n0 + 128 <= Nb);
            if (full) {
#pragma unroll
                for (int i = 0; i < 8; ++i) {
                    const int kg = k0 + wv * 8 + i;
                    const float* bp = (const float*)B + (long long)kg * ldb + ng0;
                    braw[2 * i]     = bp[0];   // ldb may be odd -> scalar loads
                    braw[2 * i + 1] = bp[1];
                }
            } else {
#pragma unroll
                for (int i = 0; i < 8; ++i) {
                    const int kg = k0 + wv * 8 + i;
                    float v0 = 0.f, v1 = 0.f;
                    if (kg < Kb) {
                        if (ng0 < Nb)     v0 = ((const float*)B)[(long long)kg * ldb + ng0];
                        if (ng0 + 1 < Nb) v1 = ((const float*)B)[(long long)kg * ldb + ng0 + 1];
                    }
                    braw[2 * i]     = v0;
                    braw[2 * i + 1] = v1;
                }
            }
        }
    };
    auto WRITEB = [&](int buf, BRAW& braw) {
        ushort8 va, vb;
        if constexpr (sizeof(TB) == 2) {
#pragma unroll
            for (int i = 0; i < 8; ++i) {
                va[i] = (u16)(braw[i] & 0xFFFFu);
                vb[i] = (u16)(braw[i] >> 16);
            }
        } else {
#pragma unroll
            for (int i = 0; i < 8; ++i) {
                va[i] = f2b(braw[2 * i]);
                vb[i] = f2b(braw[2 * i + 1]);
            }
        }
        *(ushort8*)&Bs[buf][cl0 * BS + wv * 8]       = va;
        *(ushort8*)&Bs[buf][(cl0 + 1) * BS + wv * 8] = vb;
    };
    auto MM = [&](int buf) {
        short8 bfr[4];
#pragma unroll
        for (int ni = 0; ni < 4; ++ni)
            bfr[ni] = *(const short8*)&Bs[buf][(wn * 64 + ni * 16 + l16) * BS + quad * 8];
#pragma unroll
        for (int mi = 0; mi < 4; ++mi) {
            short8 a = *(const short8*)&As[buf][(wm * 64 + mi * 16 + l16) * AS + quad * 8];
#pragma unroll
            for (int ni = 0; ni < 4; ++ni)
                acc[mi][ni] = __builtin_amdgcn_mfma_f32_16x16x32_bf16(a, bfr[ni], acc[mi][ni], 0, 0, 0);
        }
    };

    // ---- pipelined K loop --------------------------------------------------
    const int nt = K >> 5;  // all K here are multiples of 32
    {   // prologue: stage tile 0 into buf 0
        unsigned int araw[8];
        BRAW braw;
        LOADA(0, 0, araw);
        LOADB(0, braw);
        WRITEA(0, 0, araw);
        WRITEB(0, braw);
        __syncthreads();  // drains DMA (vmcnt) + ds_writes (lgkmcnt)
    }
    for (int t = 0; t < nt; ++t) {
        const int cur = t & 1, nxt = cur ^ 1;
        unsigned int araw[8];
        BRAW braw;
        const bool pf = (t + 1 < nt);
        if (pf) {                       // issue next-tile loads FIRST
            LOADA((t + 1) * 32, nxt, araw);
            LOADB((t + 1) * 32, braw);
        }
        MM(cur);                        // compute under the loads' latency
        if (pf) {                       // convert + LDS-write after compute
            WRITEA((t + 1) * 32, nxt, araw);
            WRITEB(nxt, braw);
        }
        __syncthreads();                // one barrier per K-step
    }

    // ---------------- epilogue ----------------
#pragma unroll
    for (int mi = 0; mi < 4; ++mi) {
#pragma unroll
        for (int r = 0; r < 4; ++r) {
            const int rg = m0 + wm * 64 + mi * 16 + quad * 4 + r;
            if (rg >= M) continue;
            const float rs = ROWSC ? rowsc[rg] : 1.f;
#pragma unroll
            for (int ni = 0; ni < 4; ++ni) {
                const int cg = n0 + wn * 64 + ni * 16 + l16;
                if (cg < N) {
                    float v = acc[mi][ni][r];
                    if (BIASF) v += biasp[cg];
                    if (RELUF) v = fmaxf(v, 0.f);
                    if (ROWSC) v *= rs;
                    stv(C, (long long)rg * ldc + cg, v);
                } else if (cg < NZ) {
                    stv(C, (long long)rg * ldc + cg, 0.f);  // zero K-pad cols
                }
            }
        }
    }
}

// ---------------------------------------------------------------------------
// fp32 -> bf16 bulk convert (8 elems/thread, exact grids)
// ---------------------------------------------------------------------------
__global__ __launch_bounds__(256) void cvt_k(
    const float* __restrict__ src, u16* __restrict__ dst, long long n)
{
    const long long i = ((long long)blockIdx.x * 256 + threadIdx.x) * 8;
    if (i >= n) return;
    const float4 a = *(const float4*)&src[i];
    const float4 b = *(const float4*)&src[i + 4];
    ushort8 v;
    v[0] = f2b(a.x); v[1] = f2b(a.y); v[2] = f2b(a.z); v[3] = f2b(a.w);
    v[4] = f2b(b.x); v[5] = f2b(b.y); v[6] = f2b(b.z); v[7] = f2b(b.w);
    *(ushort8*)&dst[i] = v;
}

// ---------------------------------------------------------------------------
// Softmax pass over bf16 logits: L[m,:] -> E = exp(L - rowmax) in place (bf16);
//   rsc[m] = 1/sum(E);  rsd[m,p] = 1/sum_n E[m, n*P + p]   (fp32 outputs)
// ---------------------------------------------------------------------------
__global__ __launch_bounds__(256) void softmax_k(
    u16* __restrict__ L, float* __restrict__ rsd, float* __restrict__ rsc)
{
    const int m = blockIdx.x;
    u16* row = L + (long long)m * NPDIM;
    const int tid = threadIdx.x;
    __shared__ float red[256];

    float mx = -1e30f;
    for (int i = tid * 8; i < NPDIM; i += 2048) {
        const ushort8 v = *(const ushort8*)&row[i];
#pragma unroll
        for (int j = 0; j < 8; ++j) mx = fmaxf(mx, b2f(v[j]));
    }
    red[tid] = mx;
    __syncthreads();
    for (int s = 128; s > 0; s >>= 1) {
        if (tid < s) red[tid] = fmaxf(red[tid], red[tid + s]);
        __syncthreads();
    }
    const float mxAll = red[0];
    __syncthreads();

    float sum = 0.f;
    for (int i = tid * 8; i < NPDIM; i += 2048) {
        const ushort8 v = *(const ushort8*)&row[i];
        ushort8 e;
#pragma unroll
        for (int j = 0; j < 8; ++j) {
            const float ef = __expf(b2f(v[j]) - mxAll);
            const u16 eb = f2b(ef);
            e[j] = eb;
            sum += b2f(eb);
        }
        *(ushort8*)&row[i] = e;
    }
    red[tid] = sum;
    __syncthreads();
    for (int s = 128; s > 0; s >>= 1) {
        if (tid < s) red[tid] += red[tid + s];
        __syncthreads();
    }
    if (tid == 0) rsc[m] = 1.f / red[0];
    __syncthreads();

    {   // rsd: 4 consecutive p per thread (256*4 = 1024)
        const int p0 = tid * 4;
        float s0 = 0.f, s1 = 0.f, s2 = 0.f, s3 = 0.f;
#pragma unroll
        for (int n = 0; n < NEXP; ++n) {
            const ushort4 v = *(const ushort4*)&row[n * PSLOT + p0];
            s0 += b2f(v.x); s1 += b2f(v.y); s2 += b2f(v.z); s3 += b2f(v.w);
        }
        const float4 r = {1.f / s0, 1.f / s1, 1.f / s2, 1.f / s3};
        *(float4*)&rsd[(long long)m * PSLOT + p0] = r;
    }
}

// ---------------------------------------------------------------------------
// Sum the KSPL split-K partials -> Y.  Grid sized exactly: MTOK*PSLOT/(4*256).
// ---------------------------------------------------------------------------
__global__ __launch_bounds__(256) void reduce_k(
    const float* __restrict__ Yp, float* __restrict__ Y)
{
    const long long S = (long long)MTOK * PSLOT;
    const long long i = ((long long)blockIdx.x * 256 + threadIdx.x) * 4;
    f32x4 r = *(const f32x4*)&Yp[i];
#pragma unroll
    for (int z = 1; z < KSPL; ++z) r += *(const f32x4*)&Yp[(long long)z * S + i];
    *(f32x4*)&Y[i] = r;
}

extern "C" void kernel_launch(void* const* d_in, const int* in_sizes, int n_in,
                              void* d_out, int out_size, void* d_ws, size_t ws_size,
                              hipStream_t stream)
{
    const float* x   = (const float*)d_in[0];  // [4096,1024]
    const float* phi = (const float*)d_in[1];  // [1024,16,1024]
    const float* W1  = (const float*)d_in[2];  // [16,1024,1365]
    const float* b1  = (const float*)d_in[3];  // [16,1365]
    const float* W2  = (const float*)d_in[4];  // [16,1365,1024]
    const float* b2  = (const float*)d_in[5];  // [16,1024]
    float* Y = (float*)d_out;                  // [4096,1024] fp32

    // Workspace (~253 MB). Aliases (lifetime-disjoint):
    //   phib (32 MB) overlays Ys   [phib: pre -> step1; Ys: step5 -> step6]
    //   xb   ( 8 MB) overlays Hb   [xb:   pre -> step3; Hb: step4 -> step5]
    //   Yp   (64 MB) overlays rsd+Xs+Hb [all dead by step 6]
    char* w = (char*)d_ws;
    u16*   L    = (u16*)w;   w += (size_t)MTOK * NPDIM * 2;          // 128 MB (logits -> E)
    u16*   Ys   = (u16*)w;   w += (size_t)NEXP * PSLOT * PSLOT * 2;  // 32 MB
    float* rsc  = (float*)w; w += (size_t)MTOK * 4;                  // 16 KB
    float* Yp   = (float*)w;                                         // 64 MB alias
    float* rsd  = (float*)w; w += (size_t)MTOK * PSLOT * 4;          // 16 MB
    u16*   Xs   = (u16*)w;   w += (size_t)NEXP * PSLOT * DDIM * 2;   // 32 MB
    u16*   Hb   = (u16*)w;   w += (size_t)NEXP * PSLOT * HPAD * 2;   // 45.1 MB
    u16*   phib = Ys;                                                // bf16 phi
    u16*   xb   = Hb;                                                // bf16 x

    // 0) one-shot bf16 conversions of x and phi
    cvt_k<<<dim3((MTOK * DDIM) / (8 * 256)), 256, 0, stream>>>(x, xb, (long long)MTOK * DDIM);
    cvt_k<<<dim3((DDIM * NPDIM) / (8 * 256)), 256, 0, stream>>>(phi, phib, (long long)DDIM * NPDIM);

    // 1) L = xb @ phib   [4096,16384], K=1024  (AMODE 0 DMA + raw-u32 B)
    mgemm<0, u16, u16, u16, false, false, false, false>
        <<<dim3(NPDIM / 128, MTOK / 128, 1), 256, 0, stream>>>(
        xb, 0, DDIM,  phib, 0, NPDIM,  L, 0, NPDIM,
        nullptr, nullptr, 0, nullptr,
        MTOK, NPDIM, NPDIM, DDIM, DDIM, NPDIM);

    // 2) E = exp(L - max) in place; rsd, rsc
    softmax_k<<<dim3(MTOK), 256, 0, stream>>>(L, rsd, rsc);

    // 3) Xs[np,d] = sum_m (E*rsd)[m,np] * x[m,d]   (A^T staging + scale, K=4096)
    mgemm<2, u16, u16, u16, false, false, false, false>
        <<<dim3(DDIM / 128, NPDIM / 128, 1), 256, 0, stream>>>(
        L, 0, NPDIM,  xb, 0, DDIM,  Xs, 0, DDIM,
        rsd, nullptr, 0, nullptr,
        NPDIM, DDIM, DDIM, MTOK, MTOK, DDIM);

    // 4) H = relu(Xs @ W1 + b1) per expert  [1024,1365]->[1024,1376], K=1024
    mgemm<0, u16, float, u16, true, true, false, true>
        <<<dim3((HPAD + 127) / 128, PSLOT / 128, NEXP), 256, 0, stream>>>(
        Xs, (long long)PSLOT * DDIM, DDIM,
        W1, (long long)DDIM * HDIM, HDIM,
        Hb, (long long)PSLOT * HPAD, HPAD,
        nullptr, b1, HDIM, nullptr,
        PSLOT, HDIM, HPAD, DDIM, DDIM, HDIM);

    // 5) Ys = H @ W2 + b2 per expert  [1024,1024], K=1376 (pad zeros both sides)
    mgemm<0, u16, float, u16, true, false, false, true>
        <<<dim3(PSLOT / 128, PSLOT / 128, NEXP), 256, 0, stream>>>(
        Hb, (long long)PSLOT * HPAD, HPAD,
        W2, (long long)HDIM * PSLOT, PSLOT,
        Ys, (long long)PSLOT * PSLOT, PSLOT,
        nullptr, b2, PSLOT, nullptr,
        PSLOT, PSLOT, PSLOT, HPAD, HDIM, PSLOT);

    // 6) Y[m,o] = rsc[m] * sum_np E[m,np] * Ys[np,o]   [4096,1024], K=16384
    //    Split-K x4: 1024 blocks (4/CU) so TLP hides staging latency.
    mgemm<0, u16, u16, float, false, false, true, false>
        <<<dim3(PSLOT / 128, MTOK / 128, KSPL), 256, 0, stream>>>(
        L, (long long)(NPDIM / KSPL), NPDIM,
        Ys, (long long)(NPDIM / KSPL) * PSLOT, PSLOT,
        Yp, (long long)MTOK * PSLOT, PSLOT,
        nullptr, nullptr, 0, rsc,
        MTOK, PSLOT, PSLOT, NPDIM / KSPL, NPDIM / KSPL, PSLOT);

    // 7) Y = sum_z Yp[z]
    reduce_k<<<dim3((MTOK * PSLOT) / (4 * 256)), 256, 0, stream>>>(Yp, Y);
}

// Round 4
// 1347.018 us; speedup vs baseline: 1.3964x; 1.0197x over previous
//
#include <hip/hip_runtime.h>
#include <math.h>

// Problem dims (fixed by setup_inputs)
#define MTOK 4096
#define DDIM 1024
#define NEXP 16
#define PSLOT 1024
#define NPDIM 16384   // NEXP*PSLOT
#define HDIM 1365
#define HPAD 1376     // HDIM rounded to multiple of 32 (K-tile), 16B-aligned rows
#define KSPL 4        // split-K factor for the final combine GEMM

typedef unsigned short u16;  // raw bf16
typedef __attribute__((ext_vector_type(8))) short short8;     // MFMA A/B frag (8 bf16)
typedef __attribute__((ext_vector_type(8))) unsigned short ushort8;
typedef __attribute__((ext_vector_type(4))) unsigned int uint32x4;
typedef __attribute__((ext_vector_type(4))) float f32x4;      // MFMA C/D frag

template<bool Bc, typename T, typename F> struct cond_t { using type = T; };
template<typename T, typename F> struct cond_t<false, T, F> { using type = F; };

__device__ __forceinline__ float b2f(u16 v) {
    union { unsigned int u; float f; } x;
    x.u = ((unsigned int)v) << 16;
    return x.f;
}
// integer RTNE (scalar path: epilogue/softmax)
__device__ __forceinline__ u16 f2b(float f) {
    union { float f; unsigned int u; } x;
    x.f = f;
    unsigned int r = x.u + 0x7FFFu + ((x.u >> 16) & 1u);
    return (u16)(r >> 16);
}
// HW packed RTNE convert: 2 f32 -> u32 of 2 bf16 (lo, hi). Identical to the
// integer-RTNE result for normal values. Register-only asm (scheduling-safe).
__device__ __forceinline__ unsigned int cvtpk(float lo, float hi) {
    unsigned int r;
    asm("v_cvt_pk_bf16_f32 %0, %1, %2" : "=v"(r) : "v"(lo), "v"(hi));
    return r;
}
__device__ __forceinline__ void stv(float* p, long long i, float v) { p[i] = v; }
__device__ __forceinline__ void stv(u16*  p, long long i, float v) { p[i] = f2b(v); }

// ---------------------------------------------------------------------------
// MFMA GEMM: C[M,N] = A' * B (+bias)(relu)(*rowsc), fp32 accumulate.
//   AMODE 0: A is bf16 [M,K] row-major -> global_load_lds (dims must be exact)
//   AMODE 2: A is bf16 [K,M] row-major (logical A^T), scaled by S[k][col&1023]
//   B is [K,N] row-major (fp32 or bf16), transpose-staged to Bs[n][k].
//   BCHK: per-tile wave-uniform bounds test vs (Kb, Nb); edge tiles scalar.
// 256 threads, 128x128 tile, BK=32, 4 waves (2x2), 4x4 16x16x32 frags/wave.
// 2-phase pipeline (R3) + LDS XOR-swizzle (R4):
//   staging writes hit rows (2l, 2l+1) at 20-word stride -> only 4 bank-groups
//   (16 words/bank, 2x min; measured 3.35e7 conflict cycles). Swizzling
//   elem ^= ((row>>3)&3)<<3 (byte bits [5:4], 16B alignment preserved) splits
//   each 16-lane alias group 4 ways -> 8 words/bank (minimum). Reads stay
//   <=2-way. AMODE0 As is DMA-written (linear both sides, rule #21).
// ---------------------------------------------------------------------------
template<int AMODE, typename TA, typename TB, typename TC,
         bool BIASF, bool RELUF, bool ROWSC, bool BCHK>
__global__ __launch_bounds__(256) void mgemm(
    const TA* __restrict__ A, long long sA, int lda,
    const TB* __restrict__ B, long long sB, int ldb,
    TC* __restrict__ C, long long sC, int ldc,
    const float* __restrict__ S,
    const float* __restrict__ bias, long long sBias,
    const float* __restrict__ rowsc,
    int M, int N, int NZ, int K, int Kb, int Nb)
{
    constexpr int AS = (AMODE == 0) ? 32 : 40;  // As row stride (elements)
    constexpr int BS = 40;                      // Bs row stride (elements)
    __shared__ u16 As[2][128 * AS];
    __shared__ u16 Bs[2][128 * BS];

    const int bz = blockIdx.z;
    A += (long long)bz * sA;
    B += (long long)bz * sB;
    C += (long long)bz * sC;
    const float* biasp = BIASF ? (bias + (long long)bz * sBias) : nullptr;

    // XCD-chunked swizzle (bijective: gx*gy % 8 == 0 for every launch here).
    const int gx = gridDim.x;
    const int nwg = gx * gridDim.y;
    int wg = blockIdx.x + gx * blockIdx.y;
    wg = (wg & 7) * (nwg >> 3) + (wg >> 3);
    const int m0 = (wg / gx) * 128;
    const int n0 = (wg % gx) * 128;

    const int tid  = threadIdx.x;
    const int lane = tid & 63;
    const int wv   = tid >> 6;       // wave 0..3
    const int wm   = wv & 1;         // wave row (2x2)
    const int wn   = wv >> 1;        // wave col
    const int quad = lane >> 4;
    const int l16  = lane & 15;

    // staging coords (one thread covers 2 adjacent cols x 8 k)
    const int pp   = tid & 63;
    const int cl0  = 2 * pp;         // local col pair base (A-col for AMODE2, B-col)
    const int ng0  = n0 + cl0;

    // swizzled LDS element offsets (row, k8-block of 8 elems)
    auto aoff = [&](int row, int k8) {
        int o = row * AS + k8 * 8;
        if constexpr (AMODE != 0) o ^= ((row >> 3) & 3) << 3;
        return o;
    };
    auto boff = [&](int row, int k8) {
        return (row * BS + k8 * 8) ^ (((row >> 3) & 3) << 3);
    };

    f32x4 acc[4][4];
#pragma unroll
    for (int i = 0; i < 4; ++i)
#pragma unroll
        for (int j = 0; j < 4; ++j) acc[i][j] = (f32x4){0.f, 0.f, 0.f, 0.f};

    using BRAW = typename cond_t<sizeof(TB) == 2, unsigned int[8], float[16]>::type;

    // ---- phase helpers -----------------------------------------------------
    auto LOADA = [&](int k0, int buf, unsigned int (&araw)[8], float2 (&sr)[8]) {
        if constexpr (AMODE == 0) {
            // direct-to-LDS DMA: rows 64B, dest = wave-uniform base + lane*16
#pragma unroll
            for (int q = 0; q < 2; ++q) {
                const u16* gp = A + (long long)(m0 + wv * 32 + q * 16 + (lane >> 2)) * lda
                                  + k0 + (lane & 3) * 8;
                u16* lp = &As[buf][(wv * 32 + q * 16) * 32];  // wave-uniform
                __builtin_amdgcn_global_load_lds(
                    (const __attribute__((address_space(1))) unsigned int*)gp,
                    (__attribute__((address_space(3))) unsigned int*)lp, 16, 0, 0);
            }
        } else {
            // bf16 [K,M]: raw u32 (2 cols) per k + float2 scales (prefetched)
#pragma unroll
            for (int i = 0; i < 8; ++i) {
                const long long kg = k0 + wv * 8 + i;
                araw[i] = *(const unsigned int*)((const u16*)A + kg * lda + (m0 + cl0));
                sr[i]   = *(const float2*)&S[kg * 1024 + ((m0 + cl0) & 1023)];
            }
        }
    };
    auto WRITEA = [&](int buf, unsigned int (&araw)[8], float2 (&sr)[8]) {
        if constexpr (AMODE != 0) {
            uint32x4 wa, wb;
#pragma unroll
            for (int j = 0; j < 4; ++j) {   // pair k = 2j, 2j+1 (same col)
                const unsigned int r0 = araw[2 * j], r1 = araw[2 * j + 1];
                wa[j] = cvtpk(b2f((u16)(r0 & 0xFFFFu)) * sr[2 * j].x,
                              b2f((u16)(r1 & 0xFFFFu)) * sr[2 * j + 1].x);
                wb[j] = cvtpk(b2f((u16)(r0 >> 16)) * sr[2 * j].y,
                              b2f((u16)(r1 >> 16)) * sr[2 * j + 1].y);
            }
            *(uint32x4*)&As[buf][aoff(cl0, wv)]     = wa;
            *(uint32x4*)&As[buf][aoff(cl0 + 1, wv)] = wb;
        }
    };
    auto LOADB = [&](int k0, BRAW& braw) {
        if constexpr (sizeof(TB) == 2) {
            // bf16 B users are statically in-bounds (BCHK=false): raw u32 copy
#pragma unroll
            for (int i = 0; i < 8; ++i) {
                const int kg = k0 + wv * 8 + i;
                braw[i] = *(const unsigned int*)((const u16*)B + (long long)kg * ldb + ng0);
            }
        } else {
            bool full = true;
            if constexpr (BCHK) full = (k0 + 32 <= Kb) && (n0 + 128 <= Nb);
            if (full) {
#pragma unroll
                for (int i = 0; i < 8; ++i) {
                    const int kg = k0 + wv * 8 + i;
                    const float* bp = (const float*)B + (long long)kg * ldb + ng0;
                    braw[2 * i]     = bp[0];   // ldb may be odd -> scalar loads
                    braw[2 * i + 1] = bp[1];
                }
            } else {
#pragma unroll
                for (int i = 0; i < 8; ++i) {
                    const int kg = k0 + wv * 8 + i;
                    float v0 = 0.f, v1 = 0.f;
                    if (kg < Kb) {
                        if (ng0 < Nb)     v0 = ((const float*)B)[(long long)kg * ldb + ng0];
                        if (ng0 + 1 < Nb) v1 = ((const float*)B)[(long long)kg * ldb + ng0 + 1];
                    }
                    braw[2 * i]     = v0;
                    braw[2 * i + 1] = v1;
                }
            }
        }
    };
    auto WRITEB = [&](int buf, BRAW& braw) {
        uint32x4 wa, wb;
        if constexpr (sizeof(TB) == 2) {
#pragma unroll
            for (int j = 0; j < 4; ++j) {   // repack (col-pairs) -> (k-pairs)
                const unsigned int r0 = braw[2 * j], r1 = braw[2 * j + 1];
                wa[j] = (r0 & 0xFFFFu) | (r1 << 16);
                wb[j] = (r0 >> 16) | (r1 & 0xFFFF0000u);
            }
        } else {
#pragma unroll
            for (int j = 0; j < 4; ++j) {
                wa[j] = cvtpk(braw[4 * j],     braw[4 * j + 2]);
                wb[j] = cvtpk(braw[4 * j + 1], braw[4 * j + 3]);
            }
        }
        *(uint32x4*)&Bs[buf][boff(cl0, wv)]     = wa;
        *(uint32x4*)&Bs[buf][boff(cl0 + 1, wv)] = wb;
    };
    auto MM = [&](int buf) {
        short8 bfr[4];
#pragma unroll
        for (int ni = 0; ni < 4; ++ni)
            bfr[ni] = *(const short8*)&Bs[buf][boff(wn * 64 + ni * 16 + l16, quad)];
#pragma unroll
        for (int mi = 0; mi < 4; ++mi) {
            short8 a = *(const short8*)&As[buf][aoff(wm * 64 + mi * 16 + l16, quad)];
#pragma unroll
            for (int ni = 0; ni < 4; ++ni)
                acc[mi][ni] = __builtin_amdgcn_mfma_f32_16x16x32_bf16(a, bfr[ni], acc[mi][ni], 0, 0, 0);
        }
    };

    // ---- pipelined K loop --------------------------------------------------
    const int nt = K >> 5;  // all K here are multiples of 32
    {   // prologue: stage tile 0 into buf 0
        unsigned int araw[8];
        float2 sr[8];
        BRAW braw;
        LOADA(0, 0, araw, sr);
        LOADB(0, braw);
        WRITEA(0, araw, sr);
        WRITEB(0, braw);
        __syncthreads();  // drains DMA (vmcnt) + ds_writes (lgkmcnt)
    }
    for (int t = 0; t < nt; ++t) {
        const int cur = t & 1, nxt = cur ^ 1;
        unsigned int araw[8];
        float2 sr[8];
        BRAW braw;
        const bool pf = (t + 1 < nt);
        if (pf) {                       // issue next-tile loads FIRST
            LOADA((t + 1) * 32, nxt, araw, sr);
            LOADB((t + 1) * 32, braw);
        }
        MM(cur);                        // compute under the loads' latency
        if (pf) {                       // convert + LDS-write after compute
            WRITEA(nxt, araw, sr);
            WRITEB(nxt, braw);
        }
        __syncthreads();                // one barrier per K-step
    }

    // ---------------- epilogue ----------------
#pragma unroll
    for (int mi = 0; mi < 4; ++mi) {
#pragma unroll
        for (int r = 0; r < 4; ++r) {
            const int rg = m0 + wm * 64 + mi * 16 + quad * 4 + r;
            if (rg >= M) continue;
            const float rs = ROWSC ? rowsc[rg] : 1.f;
#pragma unroll
            for (int ni = 0; ni < 4; ++ni) {
                const int cg = n0 + wn * 64 + ni * 16 + l16;
                if (cg < N) {
                    float v = acc[mi][ni][r];
                    if (BIASF) v += biasp[cg];
                    if (RELUF) v = fmaxf(v, 0.f);
                    if (ROWSC) v *= rs;
                    stv(C, (long long)rg * ldc + cg, v);
                } else if (cg < NZ) {
                    stv(C, (long long)rg * ldc + cg, 0.f);  // zero K-pad cols
                }
            }
        }
    }
}

// ---------------------------------------------------------------------------
// fp32 -> bf16 bulk convert (8 elems/thread, exact grids)
// ---------------------------------------------------------------------------
__global__ __launch_bounds__(256) void cvt_k(
    const float* __restrict__ src, u16* __restrict__ dst, long long n)
{
    const long long i = ((long long)blockIdx.x * 256 + threadIdx.x) * 8;
    if (i >= n) return;
    const float4 a = *(const float4*)&src[i];
    const float4 b = *(const float4*)&src[i + 4];
    uint32x4 v;
    v[0] = cvtpk(a.x, a.y);
    v[1] = cvtpk(a.z, a.w);
    v[2] = cvtpk(b.x, b.y);
    v[3] = cvtpk(b.z, b.w);
    *(uint32x4*)&dst[i] = v;
}

// ---------------------------------------------------------------------------
// Softmax pass over bf16 logits: L[m,:] -> E = exp(L - rowmax) in place (bf16);
//   rsc[m] = 1/sum(E);  rsd[m,p] = 1/sum_n E[m, n*P + p]   (fp32 outputs)
// ---------------------------------------------------------------------------
__global__ __launch_bounds__(256) void softmax_k(
    u16* __restrict__ L, float* __restrict__ rsd, float* __restrict__ rsc)
{
    const int m = blockIdx.x;
    u16* row = L + (long long)m * NPDIM;
    const int tid = threadIdx.x;
    __shared__ float red[256];

    float mx = -1e30f;
    for (int i = tid * 8; i < NPDIM; i += 2048) {
        const ushort8 v = *(const ushort8*)&row[i];
#pragma unroll
        for (int j = 0; j < 8; ++j) mx = fmaxf(mx, b2f(v[j]));
    }
    red[tid] = mx;
    __syncthreads();
    for (int s = 128; s > 0; s >>= 1) {
        if (tid < s) red[tid] = fmaxf(red[tid], red[tid + s]);
        __syncthreads();
    }
    const float mxAll = red[0];
    __syncthreads();

    float sum = 0.f;
    for (int i = tid * 8; i < NPDIM; i += 2048) {
        const ushort8 v = *(const ushort8*)&row[i];
        ushort8 e;
#pragma unroll
        for (int j = 0; j < 8; ++j) {
            const float ef = __expf(b2f(v[j]) - mxAll);
            const u16 eb = f2b(ef);
            e[j] = eb;
            sum += b2f(eb);
        }
        *(ushort8*)&row[i] = e;
    }
    red[tid] = sum;
    __syncthreads();
    for (int s = 128; s > 0; s >>= 1) {
        if (tid < s) red[tid] += red[tid + s];
        __syncthreads();
    }
    if (tid == 0) rsc[m] = 1.f / red[0];
    __syncthreads();

    {   // rsd: 4 consecutive p per thread (256*4 = 1024)
        const int p0 = tid * 4;
        float s0 = 0.f, s1 = 0.f, s2 = 0.f, s3 = 0.f;
#pragma unroll
        for (int n = 0; n < NEXP; ++n) {
            const ushort4 v = *(const ushort4*)&row[n * PSLOT + p0];
            s0 += b2f(v.x); s1 += b2f(v.y); s2 += b2f(v.z); s3 += b2f(v.w);
        }
        const float4 r = {1.f / s0, 1.f / s1, 1.f / s2, 1.f / s3};
        *(float4*)&rsd[(long long)m * PSLOT + p0] = r;
    }
}

// ---------------------------------------------------------------------------
// Sum the KSPL split-K partials -> Y.  Grid sized exactly: MTOK*PSLOT/(4*256).
// ---------------------------------------------------------------------------
__global__ __launch_bounds__(256) void reduce_k(
    const float* __restrict__ Yp, float* __restrict__ Y)
{
    const long long S = (long long)MTOK * PSLOT;
    const long long i = ((long long)blockIdx.x * 256 + threadIdx.x) * 4;
    f32x4 r = *(const f32x4*)&Yp[i];
#pragma unroll
    for (int z = 1; z < KSPL; ++z) r += *(const f32x4*)&Yp[(long long)z * S + i];
    *(f32x4*)&Y[i] = r;
}

extern "C" void kernel_launch(void* const* d_in, const int* in_sizes, int n_in,
                              void* d_out, int out_size, void* d_ws, size_t ws_size,
                              hipStream_t stream)
{
    const float* x   = (const float*)d_in[0];  // [4096,1024]
    const float* phi = (const float*)d_in[1];  // [1024,16,1024]
    const float* W1  = (const float*)d_in[2];  // [16,1024,1365]
    const float* b1  = (const float*)d_in[3];  // [16,1365]
    const float* W2  = (const float*)d_in[4];  // [16,1365,1024]
    const float* b2  = (const float*)d_in[5];  // [16,1024]
    float* Y = (float*)d_out;                  // [4096,1024] fp32

    // Workspace (~253 MB). Aliases (lifetime-disjoint):
    //   phib (32 MB) overlays Ys   [phib: pre -> step1; Ys: step5 -> step6]
    //   xb   ( 8 MB) overlays Hb   [xb:   pre -> step3; Hb: step4 -> step5]
    //   Yp   (64 MB) overlays rsd+Xs+Hb [all dead by step 6]
    char* w = (char*)d_ws;
    u16*   L    = (u16*)w;   w += (size_t)MTOK * NPDIM * 2;          // 128 MB (logits -> E)
    u16*   Ys   = (u16*)w;   w += (size_t)NEXP * PSLOT * PSLOT * 2;  // 32 MB
    float* rsc  = (float*)w; w += (size_t)MTOK * 4;                  // 16 KB
    float* Yp   = (float*)w;                                         // 64 MB alias
    float* rsd  = (float*)w; w += (size_t)MTOK * PSLOT * 4;          // 16 MB
    u16*   Xs   = (u16*)w;   w += (size_t)NEXP * PSLOT * DDIM * 2;   // 32 MB
    u16*   Hb   = (u16*)w;   w += (size_t)NEXP * PSLOT * HPAD * 2;   // 45.1 MB
    u16*   phib = Ys;                                                // bf16 phi
    u16*   xb   = Hb;                                                // bf16 x

    // 0) one-shot bf16 conversions of x and phi
    cvt_k<<<dim3((MTOK * DDIM) / (8 * 256)), 256, 0, stream>>>(x, xb, (long long)MTOK * DDIM);
    cvt_k<<<dim3((DDIM * NPDIM) / (8 * 256)), 256, 0, stream>>>(phi, phib, (long long)DDIM * NPDIM);

    // 1) L = xb @ phib   [4096,16384], K=1024  (AMODE 0 DMA + raw-u32 B)
    mgemm<0, u16, u16, u16, false, false, false, false>
        <<<dim3(NPDIM / 128, MTOK / 128, 1), 256, 0, stream>>>(
        xb, 0, DDIM,  phib, 0, NPDIM,  L, 0, NPDIM,
        nullptr, nullptr, 0, nullptr,
        MTOK, NPDIM, NPDIM, DDIM, DDIM, NPDIM);

    // 2) E = exp(L - max) in place; rsd, rsc
    softmax_k<<<dim3(MTOK), 256, 0, stream>>>(L, rsd, rsc);

    // 3) Xs[np,d] = sum_m (E*rsd)[m,np] * x[m,d]   (A^T staging + scale, K=4096)
    mgemm<2, u16, u16, u16, false, false, false, false>
        <<<dim3(DDIM / 128, NPDIM / 128, 1), 256, 0, stream>>>(
        L, 0, NPDIM,  xb, 0, DDIM,  Xs, 0, DDIM,
        rsd, nullptr, 0, nullptr,
        NPDIM, DDIM, DDIM, MTOK, MTOK, DDIM);

    // 4) H = relu(Xs @ W1 + b1) per expert  [1024,1365]->[1024,1376], K=1024
    mgemm<0, u16, float, u16, true, true, false, true>
        <<<dim3((HPAD + 127) / 128, PSLOT / 128, NEXP), 256, 0, stream>>>(
        Xs, (long long)PSLOT * DDIM, DDIM,
        W1, (long long)DDIM * HDIM, HDIM,
        Hb, (long long)PSLOT * HPAD, HPAD,
        nullptr, b1, HDIM, nullptr,
        PSLOT, HDIM, HPAD, DDIM, DDIM, HDIM);

    // 5) Ys = H @ W2 + b2 per expert  [1024,1024], K=1376 (pad zeros both sides)
    mgemm<0, u16, float, u16, true, false, false, true>
        <<<dim3(PSLOT / 128, PSLOT / 128, NEXP), 256, 0, stream>>>(
        Hb, (long long)PSLOT * HPAD, HPAD,
        W2, (long long)HDIM * PSLOT, PSLOT,
        Ys, (long long)PSLOT * PSLOT, PSLOT,
        nullptr, b2, PSLOT, nullptr,
        PSLOT, PSLOT, PSLOT, HPAD, HDIM, PSLOT);

    // 6) Y[m,o] = rsc[m] * sum_np E[m,np] * Ys[np,o]   [4096,1024], K=16384
    //    Split-K x4: 1024 blocks (4/CU) so TLP hides staging latency.
    mgemm<0, u16, u16, float, false, false, true, false>
        <<<dim3(PSLOT / 128, MTOK / 128, KSPL), 256, 0, stream>>>(
        L, (long long)(NPDIM / KSPL), NPDIM,
        Ys, (long long)(NPDIM / KSPL) * PSLOT, PSLOT,
        Yp, (long long)MTOK * PSLOT, PSLOT,
        nullptr, nullptr, 0, rsc,
        MTOK, PSLOT, PSLOT, NPDIM / KSPL, NPDIM / KSPL, PSLOT);

    // 7) Y = sum_z Yp[z]
    reduce_k<<<dim3((MTOK * PSLOT) / (4 * 256)), 256, 0, stream>>>(Yp, Y);
}

// Round 5
// 1163.498 us; speedup vs baseline: 1.6166x; 1.1577x over previous
//
#include <hip/hip_runtime.h>
#include <math.h>

// Problem dims (fixed by setup_inputs)
#define MTOK 4096
#define DDIM 1024
#define NEXP 16
#define PSLOT 1024
#define NPDIM 16384   // NEXP*PSLOT
#define HDIM 1365
#define HPAD 1376     // HDIM rounded to multiple of 32 (K-tile), 16B-aligned rows
#define KSPL 4        // split-K factor for the final combine GEMM

typedef unsigned short u16;  // raw bf16
typedef __attribute__((ext_vector_type(8))) short short8;     // MFMA A/B frag (8 bf16)
typedef __attribute__((ext_vector_type(8))) unsigned short ushort8;
typedef __attribute__((ext_vector_type(2))) unsigned int uint32x2;
typedef __attribute__((ext_vector_type(4))) unsigned int uint32x4;
typedef __attribute__((ext_vector_type(4))) float f32x4;      // MFMA C/D frag

template<bool Bc, typename T, typename F> struct cond_t { using type = T; };
template<typename T, typename F> struct cond_t<false, T, F> { using type = F; };

__device__ __forceinline__ float b2f(u16 v) {
    union { unsigned int u; float f; } x;
    x.u = ((unsigned int)v) << 16;
    return x.f;
}
// integer RTNE (scalar path: epilogue/softmax)
__device__ __forceinline__ u16 f2b(float f) {
    union { float f; unsigned int u; } x;
    x.f = f;
    unsigned int r = x.u + 0x7FFFu + ((x.u >> 16) & 1u);
    return (u16)(r >> 16);
}
// HW packed RTNE convert: 2 f32 -> u32 of 2 bf16 (lo, hi).
__device__ __forceinline__ unsigned int cvtpk(float lo, float hi) {
    unsigned int r;
    asm("v_cvt_pk_bf16_f32 %0, %1, %2" : "=v"(r) : "v"(lo), "v"(hi));
    return r;
}
__device__ __forceinline__ void stv(float* p, long long i, float v) { p[i] = v; }
__device__ __forceinline__ void stv(u16*  p, long long i, float v) { p[i] = f2b(v); }

// ---------------------------------------------------------------------------
// MFMA GEMM: C[M,N] = A' * B (+bias)(relu)(*rowsc), fp32 accumulate.
//   AMODE 0: A is bf16 [M,K] row-major -> global_load_lds (dims must be exact)
//   AMODE 2: A is bf16 [K,M] row-major (logical A^T), scaled by S[k][col&1023]
//   B is [K,N] row-major (fp32 or bf16), transpose-staged to Bs[n][k].
//   BCHK: per-tile wave-uniform bounds test vs (Kb, Nb); edge tiles scalar.
// R5 shape: 256x128 tile, BK=32, 512 threads / 8 waves (4 row x 2 col),
// each wave 4x4 16x16x32 frags (MM/acc/epilogue identical to the verified
// 128^2 R3/R4 template; only staging index math changed).
//   - MFMA per block-K-step 64 -> 128 at ~same per-thread staging cost
//   - LDS 52-60 KB -> 2-3 blocks/CU = 16-24 waves/CU
// 2-phase pipeline (R3): issue t+1 loads -> MFMA(t) -> convert+ds_write(t+1)
// -> one barrier. XOR swizzle on reg-staged LDS (R4). Bijective XCD swizzle
// (nwg may be !=0 mod 8 now, e.g. step 4's 44).
// ---------------------------------------------------------------------------
template<int AMODE, typename TA, typename TB, typename TC,
         bool BIASF, bool RELUF, bool ROWSC, bool BCHK>
__global__ __launch_bounds__(512) void mgemm(
    const TA* __restrict__ A, long long sA, int lda,
    const TB* __restrict__ B, long long sB, int ldb,
    TC* __restrict__ C, long long sC, int ldc,
    const float* __restrict__ S,
    const float* __restrict__ bias, long long sBias,
    const float* __restrict__ rowsc,
    int M, int N, int NZ, int K, int Kb, int Nb)
{
    constexpr int AS = (AMODE == 0) ? 32 : 40;  // As row stride (elements)
    constexpr int BS = 40;                      // Bs row stride (elements)
    __shared__ u16 As[2][256 * AS];
    __shared__ u16 Bs[2][128 * BS];

    const int bz = blockIdx.z;
    A += (long long)bz * sA;
    B += (long long)bz * sB;
    C += (long long)bz * sC;
    const float* biasp = BIASF ? (bias + (long long)bz * sBias) : nullptr;

    // Bijective XCD-chunked swizzle (m204): works for any nwg.
    const int gx = gridDim.x;
    const int nwg = gx * gridDim.y;
    int wg = blockIdx.x + gx * blockIdx.y;
    {
        const int q = nwg >> 3, r = nwg & 7, xc = wg & 7, ix = wg >> 3;
        wg = (xc < r ? xc * (q + 1) : r + xc * q) + ix;
    }
    const int m0 = (wg / gx) * 256;
    const int n0 = (wg % gx) * 128;

    const int tid  = threadIdx.x;
    const int lane = tid & 63;
    const int wv   = tid >> 6;       // wave 0..7
    const int wm   = wv & 3;         // wave row (4x2)
    const int wn   = wv >> 2;        // wave col
    const int quad = lane >> 4;
    const int l16  = lane & 15;

    // A staging coords (AMODE2): 2 adjacent cols x 8 k per thread
    const int cla  = 2 * (tid & 127);   // 128 col-pairs = 256 cols
    const int k8a  = tid >> 7;          // 0..3, 8 k each
    // B staging coords: 2 adjacent cols x 4 k per thread
    const int clb  = 2 * (tid & 63);    // 64 col-pairs = 128 cols
    const int kqb  = tid >> 6;          // 0..7, 4 k each
    const int ngb  = n0 + clb;

    // swizzled LDS element offsets (kel = element offset within the row)
    auto aoff = [&](int row, int k8) {
        int o = row * AS + k8 * 8;
        if constexpr (AMODE != 0) o ^= ((row >> 3) & 3) << 3;
        return o;
    };
    auto boff = [&](int row, int kel) {
        return (row * BS + kel) ^ (((row >> 3) & 3) << 3);
    };

    f32x4 acc[4][4];
#pragma unroll
    for (int i = 0; i < 4; ++i)
#pragma unroll
        for (int j = 0; j < 4; ++j) acc[i][j] = (f32x4){0.f, 0.f, 0.f, 0.f};

    using BRAW = typename cond_t<sizeof(TB) == 2, unsigned int[4], float[8]>::type;

    // ---- phase helpers -----------------------------------------------------
    auto LOADA = [&](int k0, int buf, unsigned int (&araw)[8], float2 (&sr)[8]) {
        if constexpr (AMODE == 0) {
            // direct-to-LDS DMA: rows 64B, dest = wave-uniform base + lane*16
#pragma unroll
            for (int q = 0; q < 2; ++q) {
                const u16* gp = A + (long long)(m0 + wv * 32 + q * 16 + (lane >> 2)) * lda
                                  + k0 + (lane & 3) * 8;
                u16* lp = &As[buf][(wv * 32 + q * 16) * 32];  // wave-uniform
                __builtin_amdgcn_global_load_lds(
                    (const __attribute__((address_space(1))) unsigned int*)gp,
                    (__attribute__((address_space(3))) unsigned int*)lp, 16, 0, 0);
            }
        } else {
            // bf16 [K,M]: raw u32 (2 cols) per k + float2 scales (prefetched)
#pragma unroll
            for (int i = 0; i < 8; ++i) {
                const long long kg = k0 + k8a * 8 + i;
                araw[i] = *(const unsigned int*)((const u16*)A + kg * lda + (m0 + cla));
                sr[i]   = *(const float2*)&S[kg * 1024 + ((m0 + cla) & 1023)];
            }
        }
    };
    auto WRITEA = [&](int buf, unsigned int (&araw)[8], float2 (&sr)[8]) {
        if constexpr (AMODE != 0) {
            uint32x4 wa, wb;
#pragma unroll
            for (int j = 0; j < 4; ++j) {   // pair k = 2j, 2j+1 (same col)
                const unsigned int r0 = araw[2 * j], r1 = araw[2 * j + 1];
                wa[j] = cvtpk(b2f((u16)(r0 & 0xFFFFu)) * sr[2 * j].x,
                              b2f((u16)(r1 & 0xFFFFu)) * sr[2 * j + 1].x);
                wb[j] = cvtpk(b2f((u16)(r0 >> 16)) * sr[2 * j].y,
                              b2f((u16)(r1 >> 16)) * sr[2 * j + 1].y);
            }
            *(uint32x4*)&As[buf][aoff(cla, k8a)]     = wa;
            *(uint32x4*)&As[buf][aoff(cla + 1, k8a)] = wb;
        }
    };
    auto LOADB = [&](int k0, BRAW& braw) {
        if constexpr (sizeof(TB) == 2) {
            // bf16 B users are statically in-bounds (BCHK=false): raw u32 copy
#pragma unroll
            for (int i = 0; i < 4; ++i) {
                const int kg = k0 + kqb * 4 + i;
                braw[i] = *(const unsigned int*)((const u16*)B + (long long)kg * ldb + ngb);
            }
        } else {
            bool full = true;
            if constexpr (BCHK) full = (k0 + 32 <= Kb) && (n0 + 128 <= Nb);
            if (full) {
#pragma unroll
                for (int i = 0; i < 4; ++i) {
                    const int kg = k0 + kqb * 4 + i;
                    const float* bp = (const float*)B + (long long)kg * ldb + ngb;
                    braw[2 * i]     = bp[0];   // ldb may be odd -> scalar loads
                    braw[2 * i + 1] = bp[1];
                }
            } else {
#pragma unroll
                for (int i = 0; i < 4; ++i) {
                    const int kg = k0 + kqb * 4 + i;
                    float v0 = 0.f, v1 = 0.f;
                    if (kg < Kb) {
                        if (ngb < Nb)     v0 = ((const float*)B)[(long long)kg * ldb + ngb];
                        if (ngb + 1 < Nb) v1 = ((const float*)B)[(long long)kg * ldb + ngb + 1];
                    }
                    braw[2 * i]     = v0;
                    braw[2 * i + 1] = v1;
                }
            }
        }
    };
    auto WRITEB = [&](int buf, BRAW& braw) {
        uint32x2 wa, wb;
        if constexpr (sizeof(TB) == 2) {
            // repack (col-pairs per k) -> (k-pairs per col)
            wa[0] = (braw[0] & 0xFFFFu) | (braw[1] << 16);
            wa[1] = (braw[2] & 0xFFFFu) | (braw[3] << 16);
            wb[0] = (braw[0] >> 16) | (braw[1] & 0xFFFF0000u);
            wb[1] = (braw[2] >> 16) | (braw[3] & 0xFFFF0000u);
        } else {
            wa[0] = cvtpk(braw[0], braw[2]);
            wa[1] = cvtpk(braw[4], braw[6]);
            wb[0] = cvtpk(braw[1], braw[3]);
            wb[1] = cvtpk(braw[5], braw[7]);
        }
        *(uint32x2*)&Bs[buf][boff(clb, kqb * 4)]     = wa;
        *(uint32x2*)&Bs[buf][boff(clb + 1, kqb * 4)] = wb;
    };
    auto MM = [&](int buf) {
        short8 bfr[4];
#pragma unroll
        for (int ni = 0; ni < 4; ++ni)
            bfr[ni] = *(const short8*)&Bs[buf][boff(wn * 64 + ni * 16 + l16, quad * 8)];
#pragma unroll
        for (int mi = 0; mi < 4; ++mi) {
            short8 a = *(const short8*)&As[buf][aoff(wm * 64 + mi * 16 + l16, quad)];
#pragma unroll
            for (int ni = 0; ni < 4; ++ni)
                acc[mi][ni] = __builtin_amdgcn_mfma_f32_16x16x32_bf16(a, bfr[ni], acc[mi][ni], 0, 0, 0);
        }
    };

    // ---- pipelined K loop --------------------------------------------------
    const int nt = K >> 5;  // all K here are multiples of 32
    {   // prologue: stage tile 0 into buf 0
        unsigned int araw[8];
        float2 sr[8];
        BRAW braw;
        LOADA(0, 0, araw, sr);
        LOADB(0, braw);
        WRITEA(0, araw, sr);
        WRITEB(0, braw);
        __syncthreads();  // drains DMA (vmcnt) + ds_writes (lgkmcnt)
    }
    for (int t = 0; t < nt; ++t) {
        const int cur = t & 1, nxt = cur ^ 1;
        unsigned int araw[8];
        float2 sr[8];
        BRAW braw;
        const bool pf = (t + 1 < nt);
        if (pf) {                       // issue next-tile loads FIRST
            LOADA((t + 1) * 32, nxt, araw, sr);
            LOADB((t + 1) * 32, braw);
        }
        MM(cur);                        // compute under the loads' latency
        if (pf) {                       // convert + LDS-write after compute
            WRITEA(nxt, araw, sr);
            WRITEB(nxt, braw);
        }
        __syncthreads();                // one barrier per K-step
    }

    // ---------------- epilogue ----------------
#pragma unroll
    for (int mi = 0; mi < 4; ++mi) {
#pragma unroll
        for (int r = 0; r < 4; ++r) {
            const int rg = m0 + wm * 64 + mi * 16 + quad * 4 + r;
            if (rg >= M) continue;
            const float rs = ROWSC ? rowsc[rg] : 1.f;
#pragma unroll
            for (int ni = 0; ni < 4; ++ni) {
                const int cg = n0 + wn * 64 + ni * 16 + l16;
                if (cg < N) {
                    float v = acc[mi][ni][r];
                    if (BIASF) v += biasp[cg];
                    if (RELUF) v = fmaxf(v, 0.f);
                    if (ROWSC) v *= rs;
                    stv(C, (long long)rg * ldc + cg, v);
                } else if (cg < NZ) {
                    stv(C, (long long)rg * ldc + cg, 0.f);  // zero K-pad cols
                }
            }
        }
    }
}

// ---------------------------------------------------------------------------
// fp32 -> bf16 bulk convert (8 elems/thread, exact grids)
// ---------------------------------------------------------------------------
__global__ __launch_bounds__(256) void cvt_k(
    const float* __restrict__ src, u16* __restrict__ dst, long long n)
{
    const long long i = ((long long)blockIdx.x * 256 + threadIdx.x) * 8;
    if (i >= n) return;
    const float4 a = *(const float4*)&src[i];
    const float4 b = *(const float4*)&src[i + 4];
    uint32x4 v;
    v[0] = cvtpk(a.x, a.y);
    v[1] = cvtpk(a.z, a.w);
    v[2] = cvtpk(b.x, b.y);
    v[3] = cvtpk(b.z, b.w);
    *(uint32x4*)&dst[i] = v;
}

// ---------------------------------------------------------------------------
// Softmax pass over bf16 logits: L[m,:] -> E = exp(L - rowmax) in place (bf16);
//   rsc[m] = 1/sum(E);  rsd[m,p] = 1/sum_n E[m, n*P + p]   (fp32 outputs)
// ---------------------------------------------------------------------------
__global__ __launch_bounds__(256) void softmax_k(
    u16* __restrict__ L, float* __restrict__ rsd, float* __restrict__ rsc)
{
    const int m = blockIdx.x;
    u16* row = L + (long long)m * NPDIM;
    const int tid = threadIdx.x;
    __shared__ float red[256];

    float mx = -1e30f;
    for (int i = tid * 8; i < NPDIM; i += 2048) {
        const ushort8 v = *(const ushort8*)&row[i];
#pragma unroll
        for (int j = 0; j < 8; ++j) mx = fmaxf(mx, b2f(v[j]));
    }
    red[tid] = mx;
    __syncthreads();
    for (int s = 128; s > 0; s >>= 1) {
        if (tid < s) red[tid] = fmaxf(red[tid], red[tid + s]);
        __syncthreads();
    }
    const float mxAll = red[0];
    __syncthreads();

    float sum = 0.f;
    for (int i = tid * 8; i < NPDIM; i += 2048) {
        const ushort8 v = *(const ushort8*)&row[i];
        ushort8 e;
#pragma unroll
        for (int j = 0; j < 8; ++j) {
            const float ef = __expf(b2f(v[j]) - mxAll);
            const u16 eb = f2b(ef);
            e[j] = eb;
            sum += b2f(eb);
        }
        *(ushort8*)&row[i] = e;
    }
    red[tid] = sum;
    __syncthreads();
    for (int s = 128; s > 0; s >>= 1) {
        if (tid < s) red[tid] += red[tid + s];
        __syncthreads();
    }
    if (tid == 0) rsc[m] = 1.f / red[0];
    __syncthreads();

    {   // rsd: 4 consecutive p per thread (256*4 = 1024)
        const int p0 = tid * 4;
        float s0 = 0.f, s1 = 0.f, s2 = 0.f, s3 = 0.f;
#pragma unroll
        for (int n = 0; n < NEXP; ++n) {
            const ushort4 v = *(const ushort4*)&row[n * PSLOT + p0];
            s0 += b2f(v.x); s1 += b2f(v.y); s2 += b2f(v.z); s3 += b2f(v.w);
        }
        const float4 r = {1.f / s0, 1.f / s1, 1.f / s2, 1.f / s3};
        *(float4*)&rsd[(long long)m * PSLOT + p0] = r;
    }
}

// ---------------------------------------------------------------------------
// Sum the KSPL split-K partials -> Y.  Grid sized exactly: MTOK*PSLOT/(4*256).
// ---------------------------------------------------------------------------
__global__ __launch_bounds__(256) void reduce_k(
    const float* __restrict__ Yp, float* __restrict__ Y)
{
    const long long S = (long long)MTOK * PSLOT;
    const long long i = ((long long)blockIdx.x * 256 + threadIdx.x) * 4;
    f32x4 r = *(const f32x4*)&Yp[i];
#pragma unroll
    for (int z = 1; z < KSPL; ++z) r += *(const f32x4*)&Yp[(long long)z * S + i];
    *(f32x4*)&Y[i] = r;
}

extern "C" void kernel_launch(void* const* d_in, const int* in_sizes, int n_in,
                              void* d_out, int out_size, void* d_ws, size_t ws_size,
                              hipStream_t stream)
{
    const float* x   = (const float*)d_in[0];  // [4096,1024]
    const float* phi = (const float*)d_in[1];  // [1024,16,1024]
    const float* W1  = (const float*)d_in[2];  // [16,1024,1365]
    const float* b1  = (const float*)d_in[3];  // [16,1365]
    const float* W2  = (const float*)d_in[4];  // [16,1365,1024]
    const float* b2  = (const float*)d_in[5];  // [16,1024]
    float* Y = (float*)d_out;                  // [4096,1024] fp32

    // Workspace (~253 MB). Aliases (lifetime-disjoint):
    //   phib (32 MB) overlays Ys   [phib: pre -> step1; Ys: step5 -> step6]
    //   xb   ( 8 MB) overlays Hb   [xb:   pre -> step3; Hb: step4 -> step5]
    //   Yp   (64 MB) overlays rsd+Xs+Hb [all dead by step 6]
    char* w = (char*)d_ws;
    u16*   L    = (u16*)w;   w += (size_t)MTOK * NPDIM * 2;          // 128 MB (logits -> E)
    u16*   Ys   = (u16*)w;   w += (size_t)NEXP * PSLOT * PSLOT * 2;  // 32 MB
    float* rsc  = (float*)w; w += (size_t)MTOK * 4;                  // 16 KB
    float* Yp   = (float*)w;                                         // 64 MB alias
    float* rsd  = (float*)w; w += (size_t)MTOK * PSLOT * 4;          // 16 MB
    u16*   Xs   = (u16*)w;   w += (size_t)NEXP * PSLOT * DDIM * 2;   // 32 MB
    u16*   Hb   = (u16*)w;   w += (size_t)NEXP * PSLOT * HPAD * 2;   // 45.1 MB
    u16*   phib = Ys;                                                // bf16 phi
    u16*   xb   = Hb;                                                // bf16 x

    // 0) one-shot bf16 conversions of x and phi
    cvt_k<<<dim3((MTOK * DDIM) / (8 * 256)), 256, 0, stream>>>(x, xb, (long long)MTOK * DDIM);
    cvt_k<<<dim3((DDIM * NPDIM) / (8 * 256)), 256, 0, stream>>>(phi, phib, (long long)DDIM * NPDIM);

    // 1) L = xb @ phib   [4096,16384], K=1024  (AMODE 0 DMA + raw-u32 B)
    mgemm<0, u16, u16, u16, false, false, false, false>
        <<<dim3(NPDIM / 128, MTOK / 256, 1), 512, 0, stream>>>(
        xb, 0, DDIM,  phib, 0, NPDIM,  L, 0, NPDIM,
        nullptr, nullptr, 0, nullptr,
        MTOK, NPDIM, NPDIM, DDIM, DDIM, NPDIM);

    // 2) E = exp(L - max) in place; rsd, rsc
    softmax_k<<<dim3(MTOK), 256, 0, stream>>>(L, rsd, rsc);

    // 3) Xs[np,d] = sum_m (E*rsd)[m,np] * x[m,d]   (A^T staging + scale, K=4096)
    mgemm<2, u16, u16, u16, false, false, false, false>
        <<<dim3(DDIM / 128, NPDIM / 256, 1), 512, 0, stream>>>(
        L, 0, NPDIM,  xb, 0, DDIM,  Xs, 0, DDIM,
        rsd, nullptr, 0, nullptr,
        NPDIM, DDIM, DDIM, MTOK, MTOK, DDIM);

    // 4) H = relu(Xs @ W1 + b1) per expert  [1024,1365]->[1024,1376], K=1024
    mgemm<0, u16, float, u16, true, true, false, true>
        <<<dim3((HPAD + 127) / 128, PSLOT / 256, NEXP), 512, 0, stream>>>(
        Xs, (long long)PSLOT * DDIM, DDIM,
        W1, (long long)DDIM * HDIM, HDIM,
        Hb, (long long)PSLOT * HPAD, HPAD,
        nullptr, b1, HDIM, nullptr,
        PSLOT, HDIM, HPAD, DDIM, DDIM, HDIM);

    // 5) Ys = H @ W2 + b2 per expert  [1024,1024], K=1376 (pad zeros both sides)
    mgemm<0, u16, float, u16, true, false, false, true>
        <<<dim3(PSLOT / 128, PSLOT / 256, NEXP), 512, 0, stream>>>(
        Hb, (long long)PSLOT * HPAD, HPAD,
        W2, (long long)HDIM * PSLOT, PSLOT,
        Ys, (long long)PSLOT * PSLOT, PSLOT,
        nullptr, b2, PSLOT, nullptr,
        PSLOT, PSLOT, PSLOT, HPAD, HDIM, PSLOT);

    // 6) Y[m,o] = rsc[m] * sum_np E[m,np] * Ys[np,o]   [4096,1024], K=16384
    //    Split-K x4: 512 blocks (2/CU) so TLP hides staging latency.
    mgemm<0, u16, u16, float, false, false, true, false>
        <<<dim3(PSLOT / 128, MTOK / 256, KSPL), 512, 0, stream>>>(
        L, (long long)(NPDIM / KSPL), NPDIM,
        Ys, (long long)(NPDIM / KSPL) * PSLOT, PSLOT,
        Yp, (long long)MTOK * PSLOT, PSLOT,
        nullptr, nullptr, 0, rsc,
        MTOK, PSLOT, PSLOT, NPDIM / KSPL, NPDIM / KSPL, PSLOT);

    // 7) Y = sum_z Yp[z]
    reduce_k<<<dim3((MTOK * PSLOT) / (4 * 256)), 256, 0, stream>>>(Yp, Y);
}